// Round 5
// baseline (315.836 us; speedup 1.0000x reference)
//
#include <hip/hip_runtime.h>
#include <hip/hip_bf16.h>
#include <hip/hip_fp16.h>

// ScannedRNN (GRU with resets), T=512 B=256 H=INP=256, MI355X gfx950.
//
// Round 5: shrink LDS traffic in the barrier-locked scan step.
//  - Weights r,z (both hid-tiles) + n-gate ht0 in VGPRs (160 regs/wave);
//    only n-gate ht1 in LDS (64 KiB). LDS instrs/step: 256 -> 192 per CU.
//  - gi block layout repacked to [g][wid][lane][ht*4+j] so each thread
//    loads ONE u16x8 (16 B) per gate per step (3 loads, fully coalesced),
//    and proj stores ONE u16x8 per gate (3 stores, full 16 B).
//  - Still: 512 thr (8 waves, 2/SIMD, 256 regs), 1 lgkm-only barrier/step,
//    gi prefetched 1 step ahead, exact reset lookback, h fp32 in regs.

#define T_LEN 512
#define BATCH 256
#define HID   256

typedef __attribute__((ext_vector_type(8))) short s16x8;          // 8 bf16
typedef __attribute__((ext_vector_type(8))) unsigned short u16x8; // 8 f16
typedef __attribute__((ext_vector_type(4))) float fx4;            // 4 f32 acc

#define MFMA16 __builtin_amdgcn_mfma_f32_16x16x32_bf16

// gi strides in halves: block = (t*16+bt), layout [g][wid][lane][ht*4+j]
#define GATE_STRIDE 4096u              /* 8 wid * 64 lane * 8 */
#define BLK_STRIDE  12288u             /* 3 gates */
#define T_STRIDE    196608u            /* 16 btiles */

__device__ __forceinline__ unsigned short f2bf(float f) {
  union { float f; unsigned u; } v; v.f = f;
  unsigned r = v.u + 0x7fffu + ((v.u >> 16) & 1u);   // RNE
  return (unsigned short)(r >> 16);
}

__device__ __forceinline__ s16x8 pack8(float4 a, float4 b) {
  s16x8 f;
  f[0] = (short)f2bf(a.x); f[1] = (short)f2bf(a.y);
  f[2] = (short)f2bf(a.z); f[3] = (short)f2bf(a.w);
  f[4] = (short)f2bf(b.x); f[5] = (short)f2bf(b.y);
  f[6] = (short)f2bf(b.z); f[7] = (short)f2bf(b.w);
  return f;
}

// 768x256 f32 weights -> bf16 MFMA B-fragments.
// Wave w owns hid-tiles {2w, 2w+1}. VGPR wr[5][8]:
//   [0]=r/ht0 [1]=r/ht1 [2]=z/ht0 [3]=z/ht1 [4]=n/ht0   (160 regs)
// LDS Wl2 (64 KiB): n-gate ht1, [w][s8][lane] 16 B lines.
__device__ __forceinline__ void load_weights(const float* __restrict__ W,
                                             s16x8 (&wr)[5][8], char* Wl2,
                                             int tid, int wid, int col, int kgrp) {
#pragma unroll
  for (int g = 0; g < 3; ++g)
#pragma unroll
    for (int ht = 0; ht < 2; ++ht) {
      if (g == 2 && ht == 1) continue;
      int row = g * 256 + (wid * 2 + ht) * 16 + col;
#pragma unroll
      for (int s8 = 0; s8 < 8; ++s8) {
        int k = s8 * 32 + kgrp * 8;
        const float4* p = (const float4*)(W + row * 256 + k);
        wr[g * 2 + ht][s8] = pack8(p[0], p[1]);
      }
    }
#pragma unroll
  for (int q = 0; q < 8; ++q) {
    int li = tid + q * 512;             // 4096 fragment lines of 16B
    int wv = li >> 9, s8 = (li >> 6) & 7, l = li & 63;
    int row = 512 + (wv * 2 + 1) * 16 + (l & 15);
    int k = s8 * 32 + (l >> 4) * 8;
    const float4* p = (const float4*)(W + row * 256 + k);
    *(s16x8*)(Wl2 + li * 16) = pack8(p[0], p[1]);
  }
}

__device__ __forceinline__ void soft_barrier() {
  asm volatile("s_waitcnt lgkmcnt(0)" ::: "memory");
  __builtin_amdgcn_s_barrier();
  __builtin_amdgcn_sched_barrier(0);
  asm volatile("" ::: "memory");
}

// ---------------- Kernel A: input projection -> gi (f16) ----------------
__global__ __launch_bounds__(512, 2) void gi_proj_kernel(
    const float* __restrict__ X, const float* __restrict__ w_ih,
    const float* __restrict__ b_ih, const float* __restrict__ b_hh,
    __half* __restrict__ gi) {
  __shared__ __align__(16) char Wl2[65536];
  __shared__ __align__(16) char Ald[2][8192];   // 16x256 bf16, swizzled, dbuf

  const int tid = threadIdx.x;
  const int wid = tid >> 6, lane = tid & 63;
  const int col = lane & 15, kgrp = lane >> 4;

  s16x8 wr[5][8];
  load_weights(w_ih, wr, Wl2, tid, wid, col, kgrp);

  float bias[2][3];
#pragma unroll
  for (int ht = 0; ht < 2; ++ht) {
    int gb = (wid * 2 + ht) * 16 + col;
    bias[ht][0] = b_ih[gb]       + b_hh[gb];        // fold b_hh for r
    bias[ht][1] = b_ih[256 + gb] + b_hh[256 + gb];  // fold b_hh for z
    bias[ht][2] = b_ih[512 + gb];                   // n: b_hh inside r*( ) in scan
  }

  const int srow = tid >> 5, sk = (tid & 31) * 8;   // 512 thr x 8 f32 = 16x256
  const unsigned sbyte = ((unsigned)(srow * 512 + sk * 2)) ^ ((unsigned)(srow & 7) << 4);

  float4 xc0 = *(const float4*)(X + (size_t)(blockIdx.x * 16 + srow) * 256 + sk);
  float4 xc1 = *(const float4*)(X + (size_t)(blockIdx.x * 16 + srow) * 256 + sk + 4);

  int parity = 0;
  for (int chunk = blockIdx.x; chunk < (T_LEN * BATCH) / 16; chunk += 256) {
    char* ab = Ald[parity];
    {
      uint4 v;
      v.x = (unsigned)f2bf(xc0.x) | ((unsigned)f2bf(xc0.y) << 16);
      v.y = (unsigned)f2bf(xc0.z) | ((unsigned)f2bf(xc0.w) << 16);
      v.z = (unsigned)f2bf(xc1.x) | ((unsigned)f2bf(xc1.y) << 16);
      v.w = (unsigned)f2bf(xc1.z) | ((unsigned)f2bf(xc1.w) << 16);
      *(uint4*)(ab + sbyte) = v;
    }
    int nchunk = chunk + 256;
    if (nchunk < (T_LEN * BATCH) / 16) {
      xc0 = *(const float4*)(X + (size_t)(nchunk * 16 + srow) * 256 + sk);
      xc1 = *(const float4*)(X + (size_t)(nchunk * 16 + srow) * 256 + sk + 4);
    }
    soft_barrier();   // stage visible; X prefetch + gi stores stay in flight

    fx4 acc[2][3];
#pragma unroll
    for (int ht = 0; ht < 2; ++ht)
#pragma unroll
      for (int g = 0; g < 3; ++g)
        acc[ht][g] = (fx4){0.f, 0.f, 0.f, 0.f};

#pragma unroll
    for (int s8 = 0; s8 < 8; ++s8) {
      unsigned aoff = ((unsigned)(col * 512 + (s8 * 32 + kgrp * 8) * 2)) ^
                      ((unsigned)(col & 7) << 4);
      s16x8 af = *(const s16x8*)(ab + aoff);
      s16x8 w2 = *(const s16x8*)(Wl2 + ((wid * 8 + s8) * 64 + lane) * 16);
      acc[0][0] = MFMA16(af, wr[0][s8], acc[0][0], 0, 0, 0);
      acc[1][0] = MFMA16(af, wr[1][s8], acc[1][0], 0, 0, 0);
      acc[0][1] = MFMA16(af, wr[2][s8], acc[0][1], 0, 0, 0);
      acc[1][1] = MFMA16(af, wr[3][s8], acc[1][1], 0, 0, 0);
      acc[0][2] = MFMA16(af, wr[4][s8], acc[0][2], 0, 0, 0);
      acc[1][2] = MFMA16(af, w2, acc[1][2], 0, 0, 0);
    }

    // store: one u16x8 per gate at [g][wid][lane][ht*4+j]
    __half* gb = gi + (size_t)chunk * BLK_STRIDE + (unsigned)(wid * 64 + lane) * 8;
#pragma unroll
    for (int g = 0; g < 3; ++g) {
      u16x8 o;
#pragma unroll
      for (int j = 0; j < 4; ++j) {
        o[j]     = __half_as_ushort(__float2half(acc[0][g][j] + bias[0][g]));
        o[4 + j] = __half_as_ushort(__float2half(acc[1][g][j] + bias[1][g]));
      }
      *(u16x8*)(gb + g * GATE_STRIDE) = o;
    }
    parity ^= 1;
  }
}

// ---------------- Kernel B: chunked GRU scan ----------------
__global__ __launch_bounds__(512, 2) void gru_scan_kernel(
    const float* __restrict__ carry, const __half* __restrict__ gi,
    const int* __restrict__ resets, const float* __restrict__ w_hh,
    const float* __restrict__ b_hh, float* __restrict__ out) {
  __shared__ __align__(16) char Wl2[65536];
  __shared__ __align__(16) char Ald[2][8192];   // h bf16 A-tile, swizzled, dbuf
  __shared__ int lastreset[16];

  const int tid = threadIdx.x;
  const int wid = tid >> 6, lane = tid & 63;
  const int col = lane & 15, kgrp = lane >> 4;
  const int bid = blockIdx.x;
  const int bt = bid & 15, c = bid >> 4;
  const int b0 = bt * 16, t0 = c * 32, t1 = t0 + 32;
  const int hid0 = wid * 32 + col;              // wave owns hid0, hid0+16

  s16x8 wr[5][8];
  load_weights(w_hh, wr, Wl2, tid, wid, col, kgrp);
  const float bhhn0 = b_hh[512 + hid0], bhhn1 = b_hh[512 + hid0 + 16];

  // ---- exact scan start: min over batch tile of (last reset < t0) ----
  int s, useCarry;
  if (c == 0) {
    s = 0; useCarry = 1;
  } else {
    if (tid < 16) lastreset[tid] = -1;
    for (int base = t0 - 32;; base -= 32) {     // 512 thr: 32 t x 16 b per pass
      __syncthreads();
      int tt = base + (tid >> 4);
      if (tt >= 0 && tt < t0) {
        if (resets[tt * BATCH + b0 + (tid & 15)] != 0)
          atomicMax(&lastreset[tid & 15], tt);
      }
      __syncthreads();
      int mn = t0, all = 1;
#pragma unroll
      for (int i = 0; i < 16; ++i) {
        int v = lastreset[i];
        all &= (v >= 0) ? 1 : 0;
        mn = min(mn, v < 0 ? t0 : v);
      }
      if (all) { s = mn; useCarry = 0; break; }
      if (base <= 0) { s = 0; useCarry = 1; break; }
    }
  }

  // ---- init state at t=s (reset[s] pre-applied) into Ald[0] ----
  {
    int row = tid >> 5, k = (tid & 31) * 8;
    int rst = resets[s * BATCH + b0 + row];
    float4 v0 = {0.f, 0.f, 0.f, 0.f}, v1 = v0;
    if (useCarry && !rst) {
      v0 = *(const float4*)(carry + (size_t)(b0 + row) * HID + k);
      v1 = *(const float4*)(carry + (size_t)(b0 + row) * HID + k + 4);
    }
    uint4 u;
    u.x = (unsigned)f2bf(v0.x) | ((unsigned)f2bf(v0.y) << 16);
    u.y = (unsigned)f2bf(v0.z) | ((unsigned)f2bf(v0.w) << 16);
    u.z = (unsigned)f2bf(v1.x) | ((unsigned)f2bf(v1.y) << 16);
    u.w = (unsigned)f2bf(v1.z) | ((unsigned)f2bf(v1.w) << 16);
    unsigned byteoff = ((unsigned)(row * 512 + k * 2)) ^ ((unsigned)(row & 7) << 4);
    *(uint4*)(Ald[0] + byteoff) = u;
  }
  float hprev[2][4];
#pragma unroll
  for (int ht = 0; ht < 2; ++ht)
#pragma unroll
    for (int j = 0; j < 4; ++j) {
      int b = kgrp * 4 + j;
      int rst = resets[s * BATCH + b0 + b];
      float hv = 0.f;
      if (useCarry && !rst) hv = carry[(size_t)(b0 + b) * HID + hid0 + ht * 16];
      hprev[ht][j] = hv;
    }
  __syncthreads();

  // ---- software-pipelined scan: gi prefetched one step ahead ----
  const __half* gp = gi + (size_t)(s * 16 + bt) * BLK_STRIDE + (unsigned)(wid * 64 + lane) * 8;
  float* op = out + 65536 + ((size_t)s * BATCH + b0 + kgrp * 4) * HID + hid0;
  const int* rbase = resets + b0 + kgrp * 4;

  u16x8 gC[3];
#pragma unroll
  for (int g = 0; g < 3; ++g)
    gC[g] = *(const u16x8*)(gp + g * GATE_STRIDE);

  for (int t = s; t < t1; ++t) {
    // resets for t+1 (used at end of this step; clamped at T-1)
    int tn = t + 1 < T_LEN ? t + 1 : T_LEN - 1;
    int4 rn = *(const int4*)(rbase + (size_t)tn * BATCH);
    // prefetch gi for t+1 (clamped re-read on last iter; values unused)
    const __half* gq = gp + ((t + 1 < t1) ? T_STRIDE : 0u);
    u16x8 gN[3];
#pragma unroll
    for (int g = 0; g < 3; ++g)
      gN[g] = *(const u16x8*)(gq + g * GATE_STRIDE);

    const char* ab = Ald[(t - s) & 1];
    fx4 acc[2][3];
#pragma unroll
    for (int ht = 0; ht < 2; ++ht)
#pragma unroll
      for (int g = 0; g < 3; ++g)
        acc[ht][g] = (fx4){0.f, 0.f, 0.f, 0.f};

#pragma unroll
    for (int s8 = 0; s8 < 8; ++s8) {
      unsigned aoff = ((unsigned)(col * 512 + (s8 * 32 + kgrp * 8) * 2)) ^
                      ((unsigned)(col & 7) << 4);
      s16x8 af = *(const s16x8*)(ab + aoff);
      s16x8 w2 = *(const s16x8*)(Wl2 + ((wid * 8 + s8) * 64 + lane) * 16);
      acc[0][0] = MFMA16(af, wr[0][s8], acc[0][0], 0, 0, 0);
      acc[1][0] = MFMA16(af, wr[1][s8], acc[1][0], 0, 0, 0);
      acc[0][1] = MFMA16(af, wr[2][s8], acc[0][1], 0, 0, 0);
      acc[1][1] = MFMA16(af, wr[3][s8], acc[1][1], 0, 0, 0);
      acc[0][2] = MFMA16(af, wr[4][s8], acc[0][2], 0, 0, 0);
      acc[1][2] = MFMA16(af, w2, acc[1][2], 0, 0, 0);
    }

    char* aw = (char*)Ald[((t - s) & 1) ^ 1];
    const bool wr_out = (t >= t0);
    const bool lastT  = (t + 1 >= T_LEN);
#pragma unroll
    for (int j = 0; j < 4; ++j) {
      int b = kgrp * 4 + j;
      int rj = (j == 0) ? rn.x : (j == 1) ? rn.y : (j == 2) ? rn.z : rn.w;
      if (lastT) rj = 0;
#pragma unroll
      for (int ht = 0; ht < 2; ++ht) {
        float pr = __half2float(__ushort_as_half(gC[0][ht * 4 + j])) + acc[ht][0][j];
        float pz = __half2float(__ushort_as_half(gC[1][ht * 4 + j])) + acc[ht][1][j];
        float r = __builtin_amdgcn_rcpf(1.f + __expf(-pr));
        float z = __builtin_amdgcn_rcpf(1.f + __expf(-pz));
        float pn = __half2float(__ushort_as_half(gC[2][ht * 4 + j])) +
                   r * (acc[ht][2][j] + (ht ? bhhn1 : bhhn0));
        float n = 1.f - 2.f * __builtin_amdgcn_rcpf(1.f + __expf(2.f * pn));
        float hnew = (1.f - z) * n + z * hprev[ht][j];
        if (wr_out) op[j * HID + ht * 16] = hnew;
        float hk = rj ? 0.f : hnew;                 // pre-apply reset[t+1]
        hprev[ht][j] = hk;
        unsigned hoff = ((unsigned)(b * 512 + (hid0 + ht * 16) * 2)) ^
                        ((unsigned)(b & 7) << 4);
        *(unsigned short*)(aw + hoff) = f2bf(hk);
      }
    }

#pragma unroll
    for (int g = 0; g < 3; ++g) gC[g] = gN[g];
    gp = gq;
    op += 65536;
    soft_barrier();   // lgkm drain only: gi prefetch + out stores stay in flight
  }

  if (c == 15) {       // h_final = h after t=511 (reset guarded off)
#pragma unroll
    for (int ht = 0; ht < 2; ++ht)
#pragma unroll
      for (int j = 0; j < 4; ++j)
        out[(size_t)(b0 + kgrp * 4 + j) * HID + hid0 + ht * 16] = hprev[ht][j];
  }
}

extern "C" void kernel_launch(void* const* d_in, const int* in_sizes, int n_in,
                              void* d_out, int out_size, void* d_ws, size_t ws_size,
                              hipStream_t stream) {
  const float* carry = (const float*)d_in[0];
  const float* X     = (const float*)d_in[1];
  const int*   rsts  = (const int*)d_in[2];
  const float* w_ih  = (const float*)d_in[3];
  const float* w_hh  = (const float*)d_in[4];
  const float* b_ih  = (const float*)d_in[5];
  const float* b_hh  = (const float*)d_in[6];
  float* out = (float*)d_out;

  const size_t gi_bytes = (size_t)T_LEN * BATCH * 3 * HID * sizeof(__half);  // 192 MiB
  if (ws_size < gi_bytes) return;
  __half* gi = (__half*)d_ws;

  gi_proj_kernel<<<256, 512, 0, stream>>>(X, w_ih, b_ih, b_hh, gi);
  gru_scan_kernel<<<256, 512, 0, stream>>>(carry, gi, rsts, w_hh, b_hh, out);
}